// Round 3
// baseline (51.399 us; speedup 1.0000x reference)
//
#include <hip/hip_runtime.h>
#include <math.h>

#define NEGS 20
#define DIMS 128
#define REGC 1e-6f
#define LPR  16            // lanes per row
#define RPW  4             // rows per wave = 64/LPR
#define HNEG 10            // negatives handled per half-wave

__device__ __forceinline__ float log_sigmoid(float x) {
    // stable: logsig(x) = min(x,0) - log(1+exp(-|x|))
    float t = __expf(-fabsf(x));
    float l = -__logf(1.f + t);
    return x >= 0.f ? l : x + l;
}

__device__ __forceinline__ float dot4(float4 a, float4 b) {
    return a.x*b.x + a.y*b.y + a.z*b.z + a.w*b.w;
}

// Work split: global wave 2p+h covers batch rows [4p, 4p+4).
//   h==0: positive dot + log_sigmoid + L1 reg term + negatives 0..9
//   h==1: negatives 10..19
// Everything reduces to one scalar, so the split needs no cross-wave data.
__global__ __launch_bounds__(256, 8) void sg_loss_kernel(
    const float* __restrict__ u_emb,
    const float* __restrict__ v_emb,
    const float* __restrict__ pretrained,
    const int* __restrict__ u_pos,
    const int* __restrict__ v_pos,
    const int* __restrict__ v_neg,
    float* __restrict__ out,
    int batch)
{
    const int lane = threadIdx.x & 63;
    const int l    = lane & (LPR - 1);     // lane within 16-lane row group
    const int g    = lane >> 4;            // row group within wave (0..3)
    const int wib  = threadIdx.x >> 6;
    const int wpb  = blockDim.x >> 6;
    const int gwave = blockIdx.x * wpb + wib;

    const int pair = gwave >> 1;           // sibling waves share rows (L1 reuse of u)
    const int half = gwave & 1;            // wave-uniform: no divergence

    const int  b     = pair * RPW + g;
    const bool valid = (b < batch);
    const int  ib    = valid ? b : 0;

    const int iu = u_pos[ib];
    const float4* up = (const float4*)(u_emb + (size_t)iu * DIMS);
    const float4 u0 = up[l], u1 = up[l + 16];

    int negidx[HNEG];
    const int nb = ib * NEGS + half * HNEG;
    #pragma unroll
    for (int n = 0; n < HNEG; ++n) negidx[n] = v_neg[nb + n];

    float part[HNEG + 1];
    float rp = 0.f;
    if (half == 0) {
        const int iv = v_pos[ib];
        const float4* vp = (const float4*)(v_emb      + (size_t)iv * DIMS);
        const float4* pp = (const float4*)(pretrained + (size_t)iu * DIMS);
        const float4 v0 = vp[l], v1 = vp[l + 16];
        part[HNEG] = dot4(u0, v0) + dot4(u1, v1);
        const float4 p0 = pp[l], p1 = pp[l + 16];
        rp = fabsf(u0.x - p0.x) + fabsf(u0.y - p0.y)
           + fabsf(u0.z - p0.z) + fabsf(u0.w - p0.w)
           + fabsf(u1.x - p1.x) + fabsf(u1.y - p1.y)
           + fabsf(u1.z - p1.z) + fabsf(u1.w - p1.w);
    } else {
        part[HNEG] = 0.f;
    }

    #pragma unroll
    for (int n = 0; n < HNEG; ++n) {
        const float4* np = (const float4*)(v_emb + (size_t)negidx[n] * DIMS);
        const float4 a = np[l], c = np[l + 16];
        part[n] = dot4(u0, a) + dot4(u1, c);
    }

    // 4-stage butterfly within each 16-lane group (11 parts + rp)
    #pragma unroll
    for (int off = 8; off > 0; off >>= 1) {
        #pragma unroll
        for (int k = 0; k <= HNEG; ++k) part[k] += __shfl_xor(part[k], off, 16);
        rp += __shfl_xor(rp, off, 16);
    }

    // group-uniform nonlinearity: 1 wave instr covers 4 rows
    float acc = 0.f;
    #pragma unroll
    for (int n = 0; n < HNEG; ++n) acc += log_sigmoid(-part[n]);
    if (half == 0) acc += log_sigmoid(part[HNEG]);

    if (!valid) { acc = 0.f; rp = 0.f; }
    float s1 = acc;
    float s2 = rp;

    // combine the 4 groups within the wave (values group-uniform)
    s1 += __shfl_xor(s1, 16, 64);  s2 += __shfl_xor(s2, 16, 64);
    s1 += __shfl_xor(s1, 32, 64);  s2 += __shfl_xor(s2, 32, 64);

    __shared__ float ls1[4], ls2[4];
    if (lane == 0) { ls1[wib] = s1; ls2[wib] = s2; }
    __syncthreads();
    if (threadIdx.x == 0) {
        float t1 = 0.f, t2 = 0.f;
        for (int w = 0; w < wpb; ++w) { t1 += ls1[w]; t2 += ls2[w]; }
        // out = -(S1)/B - REG*S2   (reg_total broadcast over B cancels the /B)
        const float contrib = -(t1 / (float)batch) - REGC * t2;
        atomicAdd(out, contrib);
    }
}

extern "C" void kernel_launch(void* const* d_in, const int* in_sizes, int n_in,
                              void* d_out, int out_size, void* d_ws, size_t ws_size,
                              hipStream_t stream) {
    const float* u_emb      = (const float*)d_in[0];
    const float* v_emb      = (const float*)d_in[1];
    const float* pretrained = (const float*)d_in[2];
    const int*   u_pos      = (const int*)d_in[3];
    const int*   v_pos      = (const int*)d_in[4];
    const int*   v_neg      = (const int*)d_in[5];
    float* out = (float*)d_out;
    const int batch = in_sizes[3];

    hipMemsetAsync(out, 0, sizeof(float), stream);

    dim3 block(256);
    // 2 waves per row-quad: nwaves = 2 * ceil(batch/RPW) = 8192 for B=16384
    int nwaves = 2 * ((batch + RPW - 1) / RPW);
    int blocks = (nwaves + 3) / 4;     // 4 waves per block -> 2048 blocks
    sg_loss_kernel<<<dim3(blocks), block, 0, stream>>>(u_emb, v_emb, pretrained,
                                                       u_pos, v_pos, v_neg, out, batch);
}